// Round 5
// baseline (410.033 us; speedup 1.0000x reference)
//
#include <hip/hip_runtime.h>
#include <cstddef>

#define B_   16
#define C_   256
#define HW_  4096

typedef __attribute__((ext_vector_type(8)))  short bf16x8;
typedef __attribute__((ext_vector_type(16))) float f32x16;

static __device__ __forceinline__ unsigned short f2bf(float f) {
    unsigned int u = __float_as_uint(f);
    u += 0x7fffu + ((u >> 16) & 1u);          // RNE
    return (unsigned short)(u >> 16);
}

// ---------------------------------------------------------------------------
// Kernel E: fused square + NCHW->NHWC bf16 + per-(b,q,h) energy argmax
// partials. grid = (b,h) = 1024 blocks x 256 thr.
// ---------------------------------------------------------------------------
__global__ __launch_bounds__(256) void fused_energy(const float* __restrict__ x,
                                                    unsigned short* __restrict__ xsqN,
                                                    float* __restrict__ pval,
                                                    int* __restrict__ pidx) {
    int blk = blockIdx.x;
    int b = blk >> 6, h = blk & 63;
    int tid = threadIdx.x;
    int w = tid & 63, layer = tid >> 6;
    __shared__ float earr[4][4][64];
    __shared__ unsigned short tile[64][264];
    float e0 = 0.f, e1 = 0.f, e2 = 0.f, e3 = 0.f;
    const float* xb = x + (size_t)b * C_ * HW_ + h * 64 + w;
#pragma unroll
    for (int i = 0; i < 8; ++i) {
        int c0 = (i * 4 + layer) * 8;
        union { unsigned short us[8]; int4 v; } u;
        float es = 0.f;
#pragma unroll
        for (int k = 0; k < 8; ++k) {
            float v = xb[(size_t)(c0 + k) * HW_];
            float s = v * v;
            es += s;
            u.us[k] = f2bf(s);
        }
        *(int4*)&tile[w][c0] = u.v;
        if ((i >> 1) == 0) e0 += es;
        else if ((i >> 1) == 1) e1 += es;
        else if ((i >> 1) == 2) e2 += es;
        else e3 += es;
    }
    earr[layer][0][w] = e0; earr[layer][1][w] = e1;
    earr[layer][2][w] = e2; earr[layer][3][w] = e3;
    __syncthreads();
    size_t base = (size_t)(b * 64 + h) * 64 * 256;
#pragma unroll
    for (int it = 0; it < 8; ++it) {
        int row  = it * 8 + (tid >> 5);
        int col8 = (tid & 31) * 8;
        *(int4*)(xsqN + base + (size_t)row * 256 + col8) = *(int4*)&tile[row][col8];
    }
    int q = tid >> 6;
    float ev = earr[0][q][w] + earr[1][q][w] + earr[2][q][w] + earr[3][q][w];
    int ix = h * 64 + w;
#pragma unroll
    for (int off = 32; off; off >>= 1) {
        float ov = __shfl_down(ev, off);
        int   oi = __shfl_down(ix, off);
        if (ov > ev || (ov == ev && oi < ix)) { ev = ov; ix = oi; }
    }
    if ((tid & 63) == 0) {
        pval[(b * 64 + h) * 4 + q] = ev;
        pidx[(b * 64 + h) * 4 + q] = ix;
    }
}

// ---------------------------------------------------------------------------
// Final argmax over h per (b,q) + Lval fill (merged). grid 64 x 64 thr.
// ---------------------------------------------------------------------------
__global__ __launch_bounds__(64) void energy_final(const float* __restrict__ pval,
                                                   const int* __restrict__ pidx,
                                                   const unsigned short* __restrict__ xsqN,
                                                   int* __restrict__ lm,
                                                   unsigned short* __restrict__ Lval) {
    int bq = blockIdx.x;
    int b = bq >> 2, q = bq & 3;
    int t = threadIdx.x;
    float ev = pval[(b * 64 + t) * 4 + q];
    int   ix = pidx[(b * 64 + t) * 4 + q];
#pragma unroll
    for (int off = 32; off; off >>= 1) {
        float ov = __shfl_down(ev, off);
        int   oi = __shfl_down(ix, off);
        if (ov > ev || (ov == ev && oi < ix)) { ev = ov; ix = oi; }
    }
    int ixw = __shfl(ix, 0);
    if (t == 0) lm[bq] = ixw;
    int hm = ixw >> 6, wm = ixw & 63;
    Lval[b * 256 + q * 64 + t] =
        xsqN[((size_t)((b * 64 + hm) * 64 + wm)) * 256 + q * 64 + t];
}

// ---------------------------------------------------------------------------
// Weight pack -> fragment-ordered bf16. Chunk (j,cib) = 16KB at (j*8+cib)<<13.
// ---------------------------------------------------------------------------
__global__ __launch_bounds__(64) void wt_pack(const float* __restrict__ w,
                                              unsigned short* __restrict__ wa) {
    int blk  = blockIdx.x;
    int lane = threadIdx.x;
    int cog = blk & 7;
    int s   = (blk >> 3) & 1;
    int cib = (blk >> 4) & 7;
    int j   = blk >> 7;
    int co  = cog * 32 + (lane & 31);
    int k0  = cib * 32 + s * 16 + (lane >> 5) * 8;
    union { unsigned short us[8]; int4 v; } u;
#pragma unroll
    for (int jj = 0; jj < 8; ++jj) {
        int ci = k0 + jj;
        u.us[jj] = f2bf(w[(size_t)(co * 256 + ci) * 9 + j]);
    }
    *(int4*)(wa + ((size_t)blk * 64 + lane) * 8) = u.v;
}

// ---------------------------------------------------------------------------
// Conv: implicit-GEMM bf16 MFMA.
// Block: 256 thr = 4 waves. Wave tile 128co x 128px (2 rows x 64 cols);
// block tile 128co x 512px (8 rows). Grid 256 = b(16) x hb(8) x wy(2).
// A fragments direct from global (packed, L1/L2-resident, prefetch 1 tap);
// B (pooled) staged in LDS, 10-row halo tile, double-buffered per 32-ci blk;
// guided-pool rect-max fused into B staging. 1 barrier per cib (8 total).
// acc = 4x4 f32x16 = 256 regs -> 1 wave/SIMD.
// ---------------------------------------------------------------------------
__global__ __launch_bounds__(256, 1) void conv_mfma(const unsigned short* __restrict__ xsqN,
                                                    const unsigned short* __restrict__ wa,
                                                    const float* __restrict__ bias,
                                                    const int* __restrict__ lm,
                                                    const unsigned short* __restrict__ Lval,
                                                    float* __restrict__ out) {
    int pt = blockIdx.x;
    int b   = pt >> 4;
    int hb  = (pt >> 1) & 7;
    int wy  = pt & 1;
    int h0g = hb * 8;
    int tid  = threadIdx.x;
    int lane = tid & 63;
    int wx   = tid >> 6;            // wave id = row-pair
    int l31 = lane & 31, qh = lane >> 5;

    __shared__ unsigned short Bs[2][26400];   // 10 rows x 66 cols x 40-pad ci

    f32x16 acc[4][4];
#pragma unroll
    for (int mt = 0; mt < 4; ++mt)
#pragma unroll
        for (int nt = 0; nt < 4; ++nt)
#pragma unroll
            for (int r = 0; r < 16; ++r) acc[mt][nt][r] = 0.f;

    int4 sv[11];     // B prefetch (next cib)
    int4 aC[8], aN[8];

    // ---- prologue: stage B(cib=0) + load A chunk (j=0,cib=0)
    {
#pragma unroll
        for (int t2 = 0; t2 < 11; ++t2) {
            int idx = tid + t2 * 256;
            int4 v = {0, 0, 0, 0};
            if (idx < 2640) {
                int pr = idx / 264; int rem = idx - pr * 264;
                int pc = rem >> 2;  int part = rem & 3;
                int grow = h0g - 1 + pr, gcol = pc - 1;
                if ((unsigned)grow < 64u && (unsigned)gcol < 64u)
                    v = *(const int4*)(xsqN + (((size_t)(b * 64 + grow) * 64 + gcol) * 256 + part * 8));
            }
            sv[t2] = v;
        }
        int l = lm[b * 4 + 0];
        int hm = l >> 6, wm = l & 63;
#pragma unroll
        for (int t2 = 0; t2 < 11; ++t2) {
            int idx = tid + t2 * 256;
            if (idx < 2640) {
                int pr = idx / 264; int rem = idx - pr * 264;
                int pc = rem >> 2;  int part = rem & 3;
                int grow = h0g - 1 + pr, gcol = pc - 1;
                union { int4 v; unsigned short us[8]; } u; u.v = sv[t2];
                bool inb = ((unsigned)grow < 64u) && ((unsigned)gcol < 64u);
                if (inb && grow <= hm && gcol <= wm) {     // quadrant 0
                    union { int4 v; unsigned short us[8]; } Lu;
                    Lu.v = *(const int4*)(Lval + b * 256 + part * 8);
#pragma unroll
                    for (int k = 0; k < 8; ++k)
                        if (Lu.us[k] > u.us[k]) u.us[k] = Lu.us[k];
                }
                *(int4*)(&Bs[0][(pr * 66 + pc) * 40 + part * 8]) = u.v;
            }
        }
#pragma unroll
        for (int s = 0; s < 2; ++s)
#pragma unroll
            for (int mt = 0; mt < 4; ++mt)
                aC[s * 4 + mt] = *(const int4*)(wa + (((s * 8 + wy * 4 + mt) * 64 + lane) << 3));
    }
    __syncthreads();

    for (int cib = 0; cib < 8; ++cib) {
        // B prefetch loads for cib+1
        if (cib < 7) {
            int nc = cib + 1;
#pragma unroll
            for (int t2 = 0; t2 < 11; ++t2) {
                int idx = tid + t2 * 256;
                int4 v = {0, 0, 0, 0};
                if (idx < 2640) {
                    int pr = idx / 264; int rem = idx - pr * 264;
                    int pc = rem >> 2;  int part = rem & 3;
                    int grow = h0g - 1 + pr, gcol = pc - 1;
                    if ((unsigned)grow < 64u && (unsigned)gcol < 64u)
                        v = *(const int4*)(xsqN + (((size_t)(b * 64 + grow) * 64 + gcol) * 256 + nc * 32 + part * 8));
                }
                sv[t2] = v;
            }
        }

        const unsigned short* Bb = &Bs[cib & 1][0];
#pragma unroll
        for (int j = 0; j < 9; ++j) {
            bool hasNext = !(j == 8 && cib == 7);
            // A prefetch for next tap
            if (hasNext) {
                int jn = (j == 8) ? 0 : j + 1;
                int cibn = (j == 8) ? cib + 1 : cib;
                const unsigned short* an = wa + ((size_t)(jn * 8 + cibn) << 13);
#pragma unroll
                for (int s = 0; s < 2; ++s)
#pragma unroll
                    for (int mt = 0; mt < 4; ++mt)
                        aN[s * 4 + mt] = *(const int4*)(an + (((s * 8 + wy * 4 + mt) * 64 + lane) << 3));
            }
            int dh = j / 3 - 1, dw = j % 3 - 1;
            int row0 = 2 * wx + dh + 1;      // 0..9
            int w0 = l31 + dw + 1;
            bf16x8 bf[8];
#pragma unroll
            for (int s = 0; s < 2; ++s)
#pragma unroll
                for (int rp = 0; rp < 2; ++rp)
#pragma unroll
                    for (int nc2 = 0; nc2 < 2; ++nc2)
                        bf[(s << 2) | (rp << 1) | nc2] =
                            *(const bf16x8*)(Bb + ((row0 + rp) * 66 + w0 + nc2 * 32) * 40 + s * 16 + qh * 8);
#pragma unroll
            for (int s = 0; s < 2; ++s) {
#pragma unroll
                for (int mt = 0; mt < 4; ++mt) {
                    bf16x8 af = *(const bf16x8*)&aC[s * 4 + mt];
#pragma unroll
                    for (int rp = 0; rp < 2; ++rp)
#pragma unroll
                        for (int nc2 = 0; nc2 < 2; ++nc2) {
                            int nt = rp * 2 + nc2;
                            acc[mt][nt] = __builtin_amdgcn_mfma_f32_32x32x16_bf16(
                                af, bf[(s << 2) | (rp << 1) | nc2], acc[mt][nt], 0, 0, 0);
                        }
                }
            }
            if (hasNext) {
#pragma unroll
                for (int k = 0; k < 8; ++k) aC[k] = aN[k];
            }
        }

        // rect-max + ds_write for cib+1 into other buffer
        if (cib < 7) {
            int nc = cib + 1;
            int l = lm[b * 4 + (nc >> 1)];
            int hm = l >> 6, wm = l & 63;
            bool qhle = (nc >> 1) < 2;
            bool qwle = ((nc >> 1) & 1) == 0;
            unsigned short* Bw = &Bs[(cib + 1) & 1][0];
#pragma unroll
            for (int t2 = 0; t2 < 11; ++t2) {
                int idx = tid + t2 * 256;
                if (idx < 2640) {
                    int pr = idx / 264; int rem = idx - pr * 264;
                    int pc = rem >> 2;  int part = rem & 3;
                    int grow = h0g - 1 + pr, gcol = pc - 1;
                    union { int4 v; unsigned short us[8]; } u; u.v = sv[t2];
                    bool inb = ((unsigned)grow < 64u) && ((unsigned)gcol < 64u);
                    bool hok = qhle ? (grow <= hm) : (grow >= hm);
                    bool wok = qwle ? (gcol <= wm) : (gcol >= wm);
                    if (inb && hok && wok) {
                        union { int4 v; unsigned short us[8]; } Lu;
                        Lu.v = *(const int4*)(Lval + b * 256 + nc * 32 + part * 8);
#pragma unroll
                        for (int k = 0; k < 8; ++k)
                            if (Lu.us[k] > u.us[k]) u.us[k] = Lu.us[k];
                    }
                    *(int4*)(&Bw[(pr * 66 + pc) * 40 + part * 8]) = u.v;
                }
            }
        }
        __syncthreads();
    }

    // ---- epilogue ----
#pragma unroll
    for (int mt = 0; mt < 4; ++mt) {
#pragma unroll
        for (int nt = 0; nt < 4; ++nt) {
            int h = h0g + 2 * wx + (nt >> 1);
            int w = (nt & 1) * 32 + l31;
#pragma unroll
            for (int r = 0; r < 16; ++r) {
                int row = (r & 3) + 8 * (r >> 2) + 4 * qh;
                int co  = wy * 128 + mt * 32 + row;
                out[(((size_t)(b * 256 + co)) * 64 + h) * 64 + w] = acc[mt][nt][r] + bias[co];
            }
        }
    }
}

// ---------------------------------------------------------------------------
extern "C" void kernel_launch(void* const* d_in, const int* in_sizes, int n_in,
                              void* d_out, int out_size, void* d_ws, size_t ws_size,
                              hipStream_t stream) {
    const float* x      = (const float*)d_in[0];
    const float* weight = (const float*)d_in[1];
    const float* bias   = (const float*)d_in[2];
    float* out = (float*)d_out;

    char* ws = (char*)d_ws;
    int*            lmp  = (int*)ws;                         // 64 ints @0
    float*          pval = (float*)(ws + 256);               // 4096 f
    int*            pidx = (int*)(ws + 256 + 16384);         // 4096 i
    unsigned short* Lval = (unsigned short*)(ws + 256 + 32768);  // 4096 ush
    unsigned short* Wa   = (unsigned short*)(ws + 49152);    // 1.18 MB
    unsigned short* xsqN = (unsigned short*)(ws + 49152 + 1179648); // NHWC bf16 33.55 MB

    hipLaunchKernelGGL(fused_energy, dim3(1024), dim3(256), 0, stream, x, xsqN, pval, pidx);
    hipLaunchKernelGGL(energy_final, dim3(64), dim3(64), 0, stream, pval, pidx, xsqN, lmp, Lval);
    hipLaunchKernelGGL(wt_pack, dim3(1152), dim3(64), 0, stream, weight, Wa);
    hipLaunchKernelGGL(conv_mfma, dim3(256), dim3(256), 0, stream, xsqN, Wa, bias, lmp, Lval, out);
}